// Round 9
// baseline (863.393 us; speedup 1.0000x reference)
//
#include <hip/hip_runtime.h>
#include <math.h>

#define B 256
#define KW 7

typedef __bf16 bf16x8 __attribute__((ext_vector_type(8)));
typedef __bf16 bf16x4 __attribute__((ext_vector_type(4)));
typedef float  f32x4  __attribute__((ext_vector_type(4)));

// ---------------------------------------------------------------------------
// helpers
// ---------------------------------------------------------------------------
__device__ __forceinline__ void block_reduce2(float& s, float& s2, float* lds) {
    for (int off = 32; off > 0; off >>= 1) {
        s  += __shfl_down(s,  off, 64);
        s2 += __shfl_down(s2, off, 64);
    }
    int wave = threadIdx.x >> 6;
    int lane = threadIdx.x & 63;
    if (lane == 0) { lds[wave * 2] = s; lds[wave * 2 + 1] = s2; }
    __syncthreads();
    if (threadIdx.x == 0) {
        s  = lds[0] + lds[2] + lds[4] + lds[6];
        s2 = lds[1] + lds[3] + lds[5] + lds[7];
    }
}

// ---------------------------------------------------------------------------
// x (B, 4, 2048) -> A0 [t][n][ci][b] fp32, LDS-tiled transpose
// ---------------------------------------------------------------------------
__global__ __launch_bounds__(256) void k_transpose(const float* __restrict__ x,
                                                   float* __restrict__ A0) {
    int bid = blockIdx.x;
    int nt  = bid & 63;
    int rem = bid >> 6;
    int ci  = rem & 1;
    int t   = rem >> 1;
    int n0  = nt * 32;
    __shared__ float lds[32][257];
    int tid = threadIdx.x;
    int nl  = tid & 31;
    int bq  = tid >> 5;
    int ch  = t * 2 + ci;
    for (int p = 0; p < 32; p++) {
        int b = bq + p * 8;
        lds[nl][b] = x[((size_t)b * 4 + ch) * 2048 + n0 + nl];
    }
    __syncthreads();
    for (int nl2 = 0; nl2 < 32; nl2++) {
        A0[(((size_t)t * 2048 + n0 + nl2) * 2 + ci) * B + tid] = lds[nl2][tid];
    }
}

// ---------------------------------------------------------------------------
// layer-1 fused conv+pool (fp32, Kt=14), output fp32 P1 [t][np][co][b]
// + per-block BN partial sums -> part1c[bid][64]
// ---------------------------------------------------------------------------
__global__ __launch_bounds__(256) void k_convpool1(
    const float* __restrict__ act,      // [2][2048][2][256]
    float* __restrict__ P1,             // [2][512][64][256] fp32
    const float* __restrict__ w,        // [64][2][7]
    const float* __restrict__ bias,
    const int* __restrict__ idx_conv,   // [7][2048]
    const int* __restrict__ idx_pool,   // [7][512]
    float* __restrict__ part1c)         // [2048][64]
{
    const int Kt = 14, C_out = 64, N_in = 2048, N_out = 512;
    int bid   = blockIdx.x;
    int cot   = bid & 1;
    int colid = bid >> 1;
    int t     = colid / N_out;
    int np    = colid - t * N_out;
    int co0   = cot << 5;

    __shared__ float lds_g[14 * 256];
    __shared__ float lds_w[14 * 33];
    __shared__ int   lds_idx[KW];

    int tid = threadIdx.x;
    int cog = tid >> 6;
    int bl  = tid & 63;

    float pmax[8][4];
    #pragma unroll
    for (int i = 0; i < 8; i++)
        #pragma unroll
        for (int j = 0; j < 4; j++) pmax[i][j] = -INFINITY;

    const float* actT = act + (size_t)t * N_in * 2 * B;

    for (int kp = 0; kp < KW; kp++) {
        int nc = idx_pool[kp * N_out + np];
        if (tid < KW) lds_idx[tid] = idx_conv[tid * N_in + nc];

        float acc[8][4];
        #pragma unroll
        for (int i = 0; i < 8; i++)
            #pragma unroll
            for (int j = 0; j < 4; j++) acc[i][j] = 0.f;

        __syncthreads();
        for (int e = tid; e < 32 * Kt; e += 256) {
            int kk = e % Kt;
            int co = e / Kt;
            lds_w[kk * 33 + co] = w[(size_t)(co0 + co) * Kt + kk];
        }
        for (int r = 0; r < Kt; r++) {
            int ci  = r / KW;
            int k   = r - ci * KW;
            int col = lds_idx[k];
            lds_g[r * 256 + tid] = actT[((size_t)col * 2 + ci) * B + tid];
        }
        __syncthreads();
        for (int kk = 0; kk < Kt; kk++) {
            float g0 = lds_g[kk * 256 + bl];
            float g1 = lds_g[kk * 256 + bl + 64];
            float g2 = lds_g[kk * 256 + bl + 128];
            float g3 = lds_g[kk * 256 + bl + 192];
            const float* wr = lds_w + kk * 33 + cog * 8;
            #pragma unroll
            for (int i = 0; i < 8; i++) {
                float wv = wr[i];
                acc[i][0] = fmaf(wv, g0, acc[i][0]);
                acc[i][1] = fmaf(wv, g1, acc[i][1]);
                acc[i][2] = fmaf(wv, g2, acc[i][2]);
                acc[i][3] = fmaf(wv, g3, acc[i][3]);
            }
        }
        #pragma unroll
        for (int i = 0; i < 8; i++)
            #pragma unroll
            for (int j = 0; j < 4; j++) pmax[i][j] = fmaxf(pmax[i][j], acc[i][j]);
    }

    float* outp = P1 + (((size_t)t * N_out + np) * C_out + co0) * B;
    float* pblk = part1c + (size_t)bid * 64;
    #pragma unroll
    for (int i = 0; i < 8; i++) {
        int co = cog * 8 + i;
        float bv = bias[co0 + co];
        float s = 0.f, s2 = 0.f;
        #pragma unroll
        for (int j = 0; j < 4; j++) {
            float val = pmax[i][j] + bv;
            outp[(size_t)co * B + bl + 64 * j] = val;
            s  += val;
            s2 += val * val;
        }
        for (int o = 32; o > 0; o >>= 1) {
            s  += __shfl_down(s,  o, 64);
            s2 += __shfl_down(s2, o, 64);
        }
        if ((tid & 63) == 0) {
            pblk[co]      = s;
            pblk[32 + co] = s2;
        }
    }
}

// ---------------------------------------------------------------------------
// BN1 stats from convpool1 partials
// ---------------------------------------------------------------------------
__global__ __launch_bounds__(256) void k_finstats1(
    const float* __restrict__ part1c,
    const float* __restrict__ gamma, const float* __restrict__ beta,
    float* __restrict__ scale, float* __restrict__ shift)
{
    int idx = blockIdx.x;            // t*64 + c
    int t = idx >> 6, c = idx & 63;
    int cot = c >> 5, cl = c & 31;
    float s = 0.f, s2 = 0.f;
    for (int np = threadIdx.x; np < 512; np += 256) {
        const float* pp = part1c + (size_t)((t * 512 + np) * 2 + cot) * 64;
        s  += pp[cl];
        s2 += pp[32 + cl];
    }
    __shared__ float lds[8];
    block_reduce2(s, s2, lds);
    if (threadIdx.x == 0) {
        float cnt  = 512.f * 256.f;
        float m    = s / cnt;
        float var  = s2 / cnt - m * m;
        float istd = rsqrtf(var + 1e-5f);
        float g    = gamma[c];
        scale[idx] = istd * g;
        shift[idx] = beta[c] - m * istd * g;
    }
}

// ---------------------------------------------------------------------------
// BN+relu + transpose: P1 fp32 [t][np][co][b] -> act1 bf16 [t][np][b][co]
// ---------------------------------------------------------------------------
__global__ __launch_bounds__(256) void k_bnrelu1t(
    const float* __restrict__ P1,
    const float* __restrict__ sc, const float* __restrict__ sh,
    __bf16* __restrict__ act1)
{
    int bid = blockIdx.x;
    int t = bid >> 9;
    int b = threadIdx.x;
    const float* src = P1 + (size_t)bid * 64 * B;
    __bf16* dst = act1 + (size_t)bid * B * 64 + (size_t)b * 64;
    const float* scp = sc + t * 64;
    const float* shp = sh + t * 64;
    __bf16 vals[64];
    #pragma unroll
    for (int co = 0; co < 64; co++) {
        float v = src[co * B + b];
        vals[co] = (__bf16)fmaxf(fmaf(v, scp[co], shp[co]), 0.f);
    }
    #pragma unroll
    for (int j = 0; j < 8; j++)
        *(bf16x8*)(dst + j * 8) = *(bf16x8*)&vals[j * 8];
}

// ---------------------------------------------------------------------------
// fused weight prep: Wr2/Wr3/Wr4 (re-layout to [co][kt][ci] bf16) + w1b (cvt8)
// ---------------------------------------------------------------------------
__global__ __launch_bounds__(256) void k_prep(
    const float* __restrict__ w2, const float* __restrict__ w3,
    const float* __restrict__ w4, const float* __restrict__ lw1,
    __bf16* __restrict__ Wr2, __bf16* __restrict__ Wr3,
    __bf16* __restrict__ Wr4, __bf16* __restrict__ w1b)
{
    const int n2 = 128 * 448, n3 = 256 * 896, n4 = 512 * 1792, n1 = (2048 * 4096) / 8;
    int idx = blockIdx.x * 256 + threadIdx.x;
    if (idx < n2) {
        int ci = idx & 63; int r = idx >> 6; int kt = r % 7; int co = r / 7;
        Wr2[idx] = (__bf16)w2[((size_t)co * 64 + ci) * 7 + kt];
        return;
    }
    idx -= n2;
    if (idx < n3) {
        int ci = idx & 127; int r = idx >> 7; int kt = r % 7; int co = r / 7;
        Wr3[idx] = (__bf16)w3[((size_t)co * 128 + ci) * 7 + kt];
        return;
    }
    idx -= n3;
    if (idx < n4) {
        int ci = idx & 255; int r = idx >> 8; int kt = r % 7; int co = r / 7;
        Wr4[idx] = (__bf16)w4[((size_t)co * 256 + ci) * 7 + kt];
        return;
    }
    idx -= n4;
    if (idx < n1) {
        const f32x4* s4 = (const f32x4*)(lw1 + (size_t)idx * 8);
        f32x4 a = s4[0], b = s4[1];
        bf16x8 v;
        v[0] = (__bf16)a[0]; v[1] = (__bf16)a[1]; v[2] = (__bf16)a[2]; v[3] = (__bf16)a[3];
        v[4] = (__bf16)b[0]; v[5] = (__bf16)b[1]; v[6] = (__bf16)b[2]; v[7] = (__bf16)b[3];
        *(bf16x8*)(w1b + (size_t)idx * 8) = v;
    }
}

// ---------------------------------------------------------------------------
// MFMA conv, barrier-free, co-tile 128 x b-tile 128 (b-split 2).
// b-split doubles block count (occupancy/latency hiding) with NO extra gather
// traffic (b partitions the column read). acc halves to 64 VGPR.
// grid: nco * N * 2t * 2bh ; block 256 (4 waves x 32 b each)
// ---------------------------------------------------------------------------
__global__ __launch_bounds__(256) void k_conv_mfma(
    const __bf16* __restrict__ act,
    __bf16* __restrict__ convo,
    const __bf16* __restrict__ wr,
    const int* __restrict__ idx_conv,   // [7][N]
    int C_in, int C_out, int N, int ci_shift)
{
    int nco = C_out >> 7;               // 128-wide co tiles
    int bid = blockIdx.x;
    int cot = bid % nco;
    int rem = bid / nco;
    int n   = rem % N;
    rem /= N;
    int t   = rem & 1;
    int bh  = rem >> 1;                 // b-half: 0 or 1
    int co0 = cot * 128;
    int Kt  = C_in * KW;

    int tid  = threadIdx.x;
    int wv   = tid >> 6;
    int lane = tid & 63;
    int quad = lane >> 4;
    int lid  = lane & 15;

    // preload all 7 gather-column indices (block-uniform -> SGPRs)
    int cols[KW];
    #pragma unroll
    for (int k = 0; k < KW; k++) cols[k] = idx_conv[k * N + n];

    f32x4 acc[8][2];
    #pragma unroll
    for (int i = 0; i < 8; i++)
        #pragma unroll
        for (int j = 0; j < 2; j++) {
            acc[i][j][0] = 0.f; acc[i][j][1] = 0.f;
            acc[i][j][2] = 0.f; acc[i][j][3] = 0.f;
        }

    // lane's base b-row: bh*128 + wv*32 + lid   (bt adds +16)
    const __bf16* actT  = act + (size_t)t * N * B * C_in
                              + ((size_t)(bh * 128 + wv * 32 + lid)) * C_in + quad * 8;
    const __bf16* wbase = wr + (size_t)(co0 + lid) * Kt + quad * 8;

    int niter = Kt >> 5;

    bf16x8 bcur[2], bnxt[2];
    {
        const __bf16* g = actT + (size_t)cols[0] * B * C_in;
        #pragma unroll
        for (int bt = 0; bt < 2; bt++)
            bcur[bt] = *(const bf16x8*)(g + (size_t)bt * 16 * C_in);
    }

    for (int it = 0; it < niter; it++) {
        int k0 = it << 5;
        // issue next iteration's gather before this iteration's MFMAs
        if (it + 1 < niter) {
            int k1  = k0 + 32;
            int kt  = k1 >> ci_shift;
            int ci0 = k1 & (C_in - 1);
            const __bf16* g = actT + (size_t)cols[kt] * B * C_in + ci0;
            #pragma unroll
            for (int bt = 0; bt < 2; bt++)
                bnxt[bt] = *(const bf16x8*)(g + (size_t)bt * 16 * C_in);
        }
        #pragma unroll
        for (int rt = 0; rt < 8; rt++) {
            bf16x8 afrag = *(const bf16x8*)(wbase + (size_t)rt * 16 * Kt + k0);
            #pragma unroll
            for (int bt = 0; bt < 2; bt++)
                acc[rt][bt] = __builtin_amdgcn_mfma_f32_16x16x32_bf16(
                    afrag, bcur[bt], acc[rt][bt], 0, 0, 0);
        }
        #pragma unroll
        for (int bt = 0; bt < 2; bt++) bcur[bt] = bnxt[bt];
    }

    __bf16* outp = convo + ((size_t)(t * N + n) * B) * C_out;
    #pragma unroll
    for (int rt = 0; rt < 8; rt++)
        #pragma unroll
        for (int bt = 0; bt < 2; bt++) {
            int b  = bh * 128 + wv * 32 + bt * 16 + lid;
            int co = co0 + rt * 16 + quad * 4;
            bf16x4 v;
            v[0] = (__bf16)acc[rt][bt][0];
            v[1] = (__bf16)acc[rt][bt][1];
            v[2] = (__bf16)acc[rt][bt][2];
            v[3] = (__bf16)acc[rt][bt][3];
            *(bf16x4*)(outp + (size_t)b * C_out + co) = v;
        }
}

// ---------------------------------------------------------------------------
// pool + bias + stats partials: convo bf16 [2][N][256][C] -> P fp32 [2][No][256][C]
// ---------------------------------------------------------------------------
__global__ __launch_bounds__(256) void k_poolstats(
    const __bf16* __restrict__ convo,
    float* __restrict__ P,
    const float* __restrict__ bias,
    const int* __restrict__ idx_pool,   // [7][No]
    float* __restrict__ part,
    int C, int N, int No)
{
    int bid  = blockIdx.x;
    int bg   = bid & 3;
    int rem  = bid >> 2;
    int np   = rem % No;
    int t    = rem / No;
    int cols[7];
    #pragma unroll
    for (int k = 0; k < 7; k++) cols[k] = idx_pool[k * No + np];
    const __bf16* base = convo + (size_t)t * N * B * C;
    float* pout = P + ((size_t)(t * No + np) * B) * C;
    int tid = threadIdx.x;
    float s[2] = {0.f, 0.f}, s2[2] = {0.f, 0.f};
    int NC, c0, bstart, bstep, nb;
    if (C >= 256) { NC = C >> 8; c0 = tid;           bstart = 0;        bstep = 1; nb = 64; }
    else          { NC = 1;      c0 = tid & (C - 1); bstart = tid >> 7; bstep = 2; nb = 32; }
    for (int j = 0; j < NC; j++) {
        int c = c0 + j * 256;
        float bv = bias[c];
        for (int i = 0; i < nb; i++) {
            int b = bg * 64 + bstart + i * bstep;
            float m = -1e30f;
            #pragma unroll
            for (int k = 0; k < 7; k++) {
                float v = (float)base[((size_t)cols[k] * B + b) * C + c];
                m = fmaxf(m, v);
            }
            float val = m + bv;
            pout[(size_t)b * C + c] = val;
            s[j] += val; s2[j] += val * val;
        }
    }
    float* pp = part + (size_t)((t * No + np) * 4 + bg) * 1024;
    for (int j = 0; j < NC; j++) {
        pp[tid + j * 256]       = s[j];
        pp[512 + tid + j * 256] = s2[j];
    }
}

// ---------------------------------------------------------------------------
// finalize BN stats from poolstats partials (one block per (t,c))
// ---------------------------------------------------------------------------
__global__ __launch_bounds__(256) void k_finstats(
    const float* __restrict__ part,
    const float* __restrict__ gamma, const float* __restrict__ beta,
    float* __restrict__ scale, float* __restrict__ shift,
    int C, int No)
{
    int idx = blockIdx.x;            // t*C + c
    int t = idx / C, c = idx - t * C;
    int SMAX   = C < 256 ? 256 : C;
    int nslice = SMAX / C;
    int nblk   = No * 4;
    int total  = nblk * nslice;
    const float* pbase = part + (size_t)(t * No * 4) * 1024;
    float s = 0.f, s2 = 0.f;
    for (int e = threadIdx.x; e < total; e += 256) {
        int blk = e / nslice;
        int j   = e - blk * nslice;
        const float* pp = pbase + (size_t)blk * 1024;
        int sl = c + j * C;
        s  += pp[sl];
        s2 += pp[512 + sl];
    }
    __shared__ float lds[8];
    block_reduce2(s, s2, lds);
    if (threadIdx.x == 0) {
        float cnt  = (float)No * 256.f;
        float m    = s / cnt;
        float var  = s2 / cnt - m * m;
        float istd = rsqrtf(var + 1e-5f);
        float g    = gamma[c];
        scale[idx] = istd * g;
        shift[idx] = beta[c] - m * istd * g;
    }
}

// ---------------------------------------------------------------------------
// BN+relu: P fp32 [2][No][256][C] -> act bf16 same layout
// ---------------------------------------------------------------------------
__global__ void k_bnrelu(const float* __restrict__ P, __bf16* __restrict__ act,
                         const float* __restrict__ scale, const float* __restrict__ shift,
                         int C, int total)
{
    int idx = blockIdx.x * 256 + threadIdx.x;
    if (idx >= total) return;
    int c = idx & (C - 1);
    int t = idx >= (total >> 1) ? 1 : 0;
    int tc = t * C + c;
    float v = P[idx];
    act[idx] = (__bf16)fmaxf(fmaf(v, scale[tc], shift[tc]), 0.f);
}

// ---------------------------------------------------------------------------
// z [b][4096] bf16 from P4 fp32 [2][8][256][512]: BN+relu+avg in fp32, one rounding
// ---------------------------------------------------------------------------
__global__ __launch_bounds__(256) void k_zbuild(const float* __restrict__ P4,
                                                const float* __restrict__ sc4,
                                                const float* __restrict__ sh4,
                                                __bf16* __restrict__ z)
{
    int b = blockIdx.x;
    int tid = threadIdx.x;
    for (int j = 0; j < 2; j++) {
        int c = tid + j * 256;
        float s0 = sc4[c],       h0 = sh4[c];
        float s1 = sc4[512 + c], h1 = sh4[512 + c];
        #pragma unroll
        for (int np = 0; np < 8; np++) {
            float v0 = P4[(((size_t)0 * 8 + np) * B + b) * 512 + c];
            float v1 = P4[(((size_t)1 * 8 + np) * B + b) * 512 + c];
            float y0 = fmaxf(fmaf(v0, s0, h0), 0.f);
            float y1 = fmaxf(fmaf(v1, s1, h1), 0.f);
            z[(size_t)b * 4096 + c * 8 + np] = (__bf16)(0.5f * (y0 + y1));
        }
    }
}

// ---------------------------------------------------------------------------
// lin1 MFMA, K-split x8, barrier-free
// ---------------------------------------------------------------------------
__global__ __launch_bounds__(256) void k_lin1_part(
    const __bf16* __restrict__ zb,    // [256][4096]
    const __bf16* __restrict__ w1b,   // [2048][4096]
    float* __restrict__ partL)        // [8][2048][256]
{
    int ht = blockIdx.x >> 3;
    int ks = blockIdx.x & 7;
    int h0 = ht * 64;
    int f_beg = ks * 512, f_end = f_beg + 512;

    int tid  = threadIdx.x;
    int wv   = tid >> 6;
    int lane = tid & 63;
    int quad = lane >> 4;
    int lid  = lane & 15;

    f32x4 acc[4][4];
    #pragma unroll
    for (int i = 0; i < 4; i++)
        #pragma unroll
        for (int j = 0; j < 4; j++) {
            acc[i][j][0] = 0.f; acc[i][j][1] = 0.f;
            acc[i][j][2] = 0.f; acc[i][j][3] = 0.f;
        }

    const __bf16* wbase = w1b + (size_t)(h0 + lid) * 4096 + quad * 8;
    const __bf16* zbase = zb + ((size_t)(wv * 64 + lid)) * 4096 + quad * 8;

    for (int f0 = f_beg; f0 < f_end; f0 += 32) {
        bf16x8 afrag[4];
        #pragma unroll
        for (int rt = 0; rt < 4; rt++)
            afrag[rt] = *(const bf16x8*)(wbase + (size_t)rt * 16 * 4096 + f0);
        bf16x8 bfrag[4];
        #pragma unroll
        for (int bt = 0; bt < 4; bt++)
            bfrag[bt] = *(const bf16x8*)(zbase + (size_t)bt * 16 * 4096 + f0);
        #pragma unroll
        for (int rt = 0; rt < 4; rt++)
            #pragma unroll
            for (int bt = 0; bt < 4; bt++)
                acc[rt][bt] = __builtin_amdgcn_mfma_f32_16x16x32_bf16(
                    afrag[rt], bfrag[bt], acc[rt][bt], 0, 0, 0);
    }
    float* outp = partL + (size_t)ks * 2048 * B;
    #pragma unroll
    for (int rt = 0; rt < 4; rt++)
        #pragma unroll
        for (int bt = 0; bt < 4; bt++) {
            int b = wv * 64 + bt * 16 + lid;
            int h = h0 + rt * 16 + quad * 4;
            #pragma unroll
            for (int r = 0; r < 4; r++)
                outp[(size_t)(h + r) * B + b] = acc[rt][bt][r];
        }
}

// ---------------------------------------------------------------------------
// reduce lin1 partials + bias -> o1, and BN5 stats, in one pass. grid 2048.
// ---------------------------------------------------------------------------
__global__ __launch_bounds__(256) void k_redstats5(
    const float* __restrict__ partL,  // [8][2048][256]
    const float* __restrict__ b1,
    const float* __restrict__ gamma5, const float* __restrict__ beta5,
    float* __restrict__ o1,           // [2048][256]
    float* __restrict__ scale5, float* __restrict__ shift5)
{
    int h = blockIdx.x;
    int b = threadIdx.x;
    float v = b1[h];
    #pragma unroll
    for (int s = 0; s < 8; s++)
        v += partL[((size_t)s * 2048 + h) * B + b];
    o1[(size_t)h * B + b] = v;
    float s1 = v, s2 = v * v;
    __shared__ float lds[8];
    block_reduce2(s1, s2, lds);
    if (threadIdx.x == 0) {
        float m    = s1 * (1.f / 256.f);
        float var  = s2 * (1.f / 256.f) - m * m;
        float istd = rsqrtf(var + 1e-5f);
        float g    = gamma5[h];
        scale5[h]  = istd * g;
        shift5[h]  = beta5[h] - m * istd * g;
    }
}

// ---------------------------------------------------------------------------
// final head
// ---------------------------------------------------------------------------
__global__ __launch_bounds__(256) void k_final(
    const float* __restrict__ o1,
    const float* __restrict__ scale5, const float* __restrict__ shift5,
    const float* __restrict__ w2, const float* __restrict__ b2,
    float* __restrict__ out)
{
    int b = blockIdx.x;
    int tid = threadIdx.x;
    float s0 = 0.f, s1 = 0.f, s2v = 0.f;
    for (int h = tid; h < 2048; h += 256) {
        float y = fmaxf(fmaf(o1[(size_t)h * B + b], scale5[h], shift5[h]), 0.f);
        s0  = fmaf(y, w2[h],        s0);
        s1  = fmaf(y, w2[2048 + h], s1);
        s2v = fmaf(y, w2[4096 + h], s2v);
    }
    for (int off = 32; off > 0; off >>= 1) {
        s0  += __shfl_down(s0,  off, 64);
        s1  += __shfl_down(s1,  off, 64);
        s2v += __shfl_down(s2v, off, 64);
    }
    __shared__ float lds[12];
    int wave = tid >> 6, lane = tid & 63;
    if (lane == 0) { lds[wave * 3] = s0; lds[wave * 3 + 1] = s1; lds[wave * 3 + 2] = s2v; }
    __syncthreads();
    if (tid == 0) {
        float o0 = lds[0] + lds[3] + lds[6] + lds[9]  + b2[0];
        float oa = lds[1] + lds[4] + lds[7] + lds[10] + b2[1];
        float ob = lds[2] + lds[5] + lds[8] + lds[11] + b2[2];
        float m   = fmaxf(o0, oa);
        float lse = m + logf(expf(o0 - m) + expf(oa - m));
        out[b * 3 + 0] = o0 - lse;
        out[b * 3 + 1] = oa - lse;
        out[b * 3 + 2] = ob;
    }
}

// ---------------------------------------------------------------------------
extern "C" void kernel_launch(void* const* d_in, const int* in_sizes, int n_in,
                              void* d_out, int out_size, void* d_ws, size_t ws_size,
                              hipStream_t stream) {
    (void)in_sizes; (void)n_in; (void)out_size; (void)ws_size;

    const float* x   = (const float*)d_in[0];
    const int*   ic1 = (const int*)d_in[1];
    const int*   ip1 = (const int*)d_in[2];
    const float* pW1 = (const float*)d_in[3];
    const float* pB1 = (const float*)d_in[4];
    const float* pG1 = (const float*)d_in[5];
    const float* pE1 = (const float*)d_in[6];
    const int*   ic2 = (const int*)d_in[7];
    const int*   ip2 = (const int*)d_in[8];
    const float* pW2 = (const float*)d_in[9];
    const float* pB2 = (const float*)d_in[10];
    const float* pG2 = (const float*)d_in[11];
    const float* pE2 = (const float*)d_in[12];
    const int*   ic3 = (const int*)d_in[13];
    const int*   ip3 = (const int*)d_in[14];
    const float* pW3 = (const float*)d_in[15];
    const float* pB3 = (const float*)d_in[16];
    const float* pG3 = (const float*)d_in[17];
    const float* pE3 = (const float*)d_in[18];
    const int*   ic4 = (const int*)d_in[19];
    const int*   ip4 = (const int*)d_in[20];
    const float* pW4 = (const float*)d_in[21];
    const float* pB4 = (const float*)d_in[22];
    const float* pG4 = (const float*)d_in[23];
    const float* pE4 = (const float*)d_in[24];
    const float* lw1 = (const float*)d_in[25];
    const float* lb1 = (const float*)d_in[26];
    const float* g5  = (const float*)d_in[27];
    const float* e5  = (const float*)d_in[28];
    const float* lw2 = (const float*)d_in[29];
    const float* lb2 = (const float*)d_in[30];

    char* ws = (char*)d_ws;
    size_t off = 0;
    auto alloc = [&](size_t bytes) -> char* {
        char* p = ws + off;
        off += (bytes + 511) & ~(size_t)511;
        return p;
    };

    float*  A0    = (float*) alloc((size_t)2 * 2048 * 2 * B * 4);      //   8.4 MB
    __bf16* act1  = (__bf16*)alloc((size_t)2 * 512 * B * 64 * 2);      //  33.5 MB
    char*   U     =          alloc((size_t)512 * B * 128 * 4);         //  67.1 MB
    float*  P1f   = (float*)U;            // layer-1 conv+pool out (dead after bnrelu1t)
    __bf16* convX = (__bf16*)U;           // bf16 conv out: L2 67MB, L3 33.5MB, L4 8.4MB
    float*  partL = (float*)U;            // lin1 K-split partials [8][2048][256] (16.8 MB)
    float*  Pf    = (float*) alloc((size_t)2 * 128 * B * 128 * 4);     //  33.5 MB
    __bf16* actS  = (__bf16*)alloc((size_t)2 * 128 * B * 128 * 2);     //  16.8 MB
    __bf16* Wr2   = (__bf16*)alloc((size_t)128 * 448 * 2);
    __bf16* Wr3   = (__bf16*)alloc((size_t)256 * 896 * 2);
    __bf16* Wr4   = (__bf16*)alloc((size_t)512 * 1792 * 2);
    __bf16* w1b   = (__bf16*)alloc((size_t)2048 * 4096 * 2);           //  16.8 MB
    __bf16* z     = (__bf16*)alloc((size_t)256 * 4096 * 2);            //   2.1 MB
    float*  o1    = (float*) alloc((size_t)2048 * B * 4);              //   2.1 MB
    float*  part  = (float*) alloc((size_t)2 * 128 * 4 * 1024 * 4);    //   4.2 MB
    float*  part1c= (float*) alloc((size_t)2048 * 64 * 4);             //   0.5 MB
    float*  sc1 = (float*)alloc(2 * 64 * 4);
    float*  sh1 = (float*)alloc(2 * 64 * 4);
    float*  sc2 = (float*)alloc(2 * 128 * 4);
    float*  sh2 = (float*)alloc(2 * 128 * 4);
    float*  sc3 = (float*)alloc(2 * 256 * 4);
    float*  sh3 = (float*)alloc(2 * 256 * 4);
    float*  sc4 = (float*)alloc(2 * 512 * 4);
    float*  sh4 = (float*)alloc(2 * 512 * 4);
    float*  sc5 = (float*)alloc(2048 * 4);
    float*  sh5 = (float*)alloc(2048 * 4);

    // fused weight prep (Wr2+Wr3+Wr4+w1b in one dispatch)
    {
        const int total = 128 * 448 + 256 * 896 + 512 * 1792 + (2048 * 4096) / 8;
        k_prep<<<(total + 255) / 256, 256, 0, stream>>>(pW2, pW3, pW4, lw1,
                                                        Wr2, Wr3, Wr4, w1b);
    }

    // input transform
    k_transpose<<<256, 256, 0, stream>>>(x, A0);

    // layer 1 (fp32; BN partials fused)
    k_convpool1<<<2048, 256, 0, stream>>>(A0, P1f, pW1, pB1, ic1, ip1, part1c);
    k_finstats1<<<2 * 64, 256, 0, stream>>>(part1c, pG1, pE1, sc1, sh1);
    k_bnrelu1t<<<2 * 512, 256, 0, stream>>>(P1f, sc1, sh1, act1);

    // layer 2: 64 -> 128, N 512 -> 128  (b-split 2: grid 2048)
    k_conv_mfma<<<1 * 512 * 2 * 2, 256, 0, stream>>>(act1, convX, Wr2, ic2, 64, 128, 512, 6);
    k_poolstats<<<2 * 128 * 4, 256, 0, stream>>>(convX, Pf, pB2, ip2, part, 128, 512, 128);
    k_finstats<<<2 * 128, 256, 0, stream>>>(part, pG2, pE2, sc2, sh2, 128, 128);
    k_bnrelu<<<(2 * 128 * B * 128) / 256, 256, 0, stream>>>(Pf, actS, sc2, sh2, 128, 2 * 128 * B * 128);

    // layer 3: 128 -> 256, N 128 -> 32  (b-split 2: grid 1024)
    k_conv_mfma<<<2 * 128 * 2 * 2, 256, 0, stream>>>(actS, convX, Wr3, ic3, 128, 256, 128, 7);
    k_poolstats<<<2 * 32 * 4, 256, 0, stream>>>(convX, Pf, pB3, ip3, part, 256, 128, 32);
    k_finstats<<<2 * 256, 256, 0, stream>>>(part, pG3, pE3, sc3, sh3, 256, 32);
    k_bnrelu<<<(2 * 32 * B * 256) / 256, 256, 0, stream>>>(Pf, actS, sc3, sh3, 256, 2 * 32 * B * 256);

    // layer 4: 256 -> 512, N 32 -> 8  (b-split 2: grid 512)
    k_conv_mfma<<<4 * 32 * 2 * 2, 256, 0, stream>>>(actS, convX, Wr4, ic4, 256, 512, 32, 8);
    k_poolstats<<<2 * 8 * 4, 256, 0, stream>>>(convX, Pf, pB4, ip4, part, 512, 32, 8);
    k_finstats<<<2 * 512, 256, 0, stream>>>(part, pG4, pE4, sc4, sh4, 512, 8);

    // head
    k_zbuild<<<256, 256, 0, stream>>>(Pf, sc4, sh4, z);
    k_lin1_part<<<256, 256, 0, stream>>>(z, w1b, partL);
    k_redstats5<<<2048, 256, 0, stream>>>(partL, lb1, g5, e5, o1, sc5, sh5);
    k_final<<<256, 256, 0, stream>>>(o1, sc5, sh5, lw2, lb2, (float*)d_out);
}

// Round 10
// 615.245 us; speedup vs baseline: 1.4033x; 1.4033x over previous
//
#include <hip/hip_runtime.h>
#include <math.h>

#define B 256
#define KW 7

typedef __bf16 bf16x8 __attribute__((ext_vector_type(8)));
typedef __bf16 bf16x4 __attribute__((ext_vector_type(4)));
typedef float  f32x4  __attribute__((ext_vector_type(4)));

#define LDSW 36   // padded row stride (bf16) for 32-elem weight rows

// ---------------------------------------------------------------------------
// helpers
// ---------------------------------------------------------------------------
__device__ __forceinline__ void block_reduce2(float& s, float& s2, float* lds) {
    for (int off = 32; off > 0; off >>= 1) {
        s  += __shfl_down(s,  off, 64);
        s2 += __shfl_down(s2, off, 64);
    }
    int wave = threadIdx.x >> 6;
    int lane = threadIdx.x & 63;
    if (lane == 0) { lds[wave * 2] = s; lds[wave * 2 + 1] = s2; }
    __syncthreads();
    if (threadIdx.x == 0) {
        s  = lds[0] + lds[2] + lds[4] + lds[6];
        s2 = lds[1] + lds[3] + lds[5] + lds[7];
    }
}

// ---------------------------------------------------------------------------
// x (B, 4, 2048) -> A0 [t][n][ci][b] fp32, LDS-tiled transpose
// ---------------------------------------------------------------------------
__global__ __launch_bounds__(256) void k_transpose(const float* __restrict__ x,
                                                   float* __restrict__ A0) {
    int bid = blockIdx.x;
    int nt  = bid & 63;
    int rem = bid >> 6;
    int ci  = rem & 1;
    int t   = rem >> 1;
    int n0  = nt * 32;
    __shared__ float lds[32][257];
    int tid = threadIdx.x;
    int nl  = tid & 31;
    int bq  = tid >> 5;
    int ch  = t * 2 + ci;
    for (int p = 0; p < 32; p++) {
        int b = bq + p * 8;
        lds[nl][b] = x[((size_t)b * 4 + ch) * 2048 + n0 + nl];
    }
    __syncthreads();
    for (int nl2 = 0; nl2 < 32; nl2++) {
        A0[(((size_t)t * 2048 + n0 + nl2) * 2 + ci) * B + tid] = lds[nl2][tid];
    }
}

// ---------------------------------------------------------------------------
// layer-1 fused conv+pool (fp32, Kt=14), output fp32 P1 [t][np][co][b]
// + per-block BN partial sums -> part1c[bid][64]
// ---------------------------------------------------------------------------
__global__ __launch_bounds__(256) void k_convpool1(
    const float* __restrict__ act,      // [2][2048][2][256]
    float* __restrict__ P1,             // [2][512][64][256] fp32
    const float* __restrict__ w,        // [64][2][7]
    const float* __restrict__ bias,
    const int* __restrict__ idx_conv,   // [7][2048]
    const int* __restrict__ idx_pool,   // [7][512]
    float* __restrict__ part1c)         // [2048][64]
{
    const int Kt = 14, C_out = 64, N_in = 2048, N_out = 512;
    int bid   = blockIdx.x;
    int cot   = bid & 1;
    int colid = bid >> 1;
    int t     = colid / N_out;
    int np    = colid - t * N_out;
    int co0   = cot << 5;

    __shared__ float lds_g[14 * 256];
    __shared__ float lds_w[14 * 33];
    __shared__ int   lds_idx[KW];

    int tid = threadIdx.x;
    int cog = tid >> 6;
    int bl  = tid & 63;

    float pmax[8][4];
    #pragma unroll
    for (int i = 0; i < 8; i++)
        #pragma unroll
        for (int j = 0; j < 4; j++) pmax[i][j] = -INFINITY;

    const float* actT = act + (size_t)t * N_in * 2 * B;

    for (int kp = 0; kp < KW; kp++) {
        int nc = idx_pool[kp * N_out + np];
        if (tid < KW) lds_idx[tid] = idx_conv[tid * N_in + nc];

        float acc[8][4];
        #pragma unroll
        for (int i = 0; i < 8; i++)
            #pragma unroll
            for (int j = 0; j < 4; j++) acc[i][j] = 0.f;

        __syncthreads();
        for (int e = tid; e < 32 * Kt; e += 256) {
            int kk = e % Kt;
            int co = e / Kt;
            lds_w[kk * 33 + co] = w[(size_t)(co0 + co) * Kt + kk];
        }
        for (int r = 0; r < Kt; r++) {
            int ci  = r / KW;
            int k   = r - ci * KW;
            int col = lds_idx[k];
            lds_g[r * 256 + tid] = actT[((size_t)col * 2 + ci) * B + tid];
        }
        __syncthreads();
        for (int kk = 0; kk < Kt; kk++) {
            float g0 = lds_g[kk * 256 + bl];
            float g1 = lds_g[kk * 256 + bl + 64];
            float g2 = lds_g[kk * 256 + bl + 128];
            float g3 = lds_g[kk * 256 + bl + 192];
            const float* wr = lds_w + kk * 33 + cog * 8;
            #pragma unroll
            for (int i = 0; i < 8; i++) {
                float wv = wr[i];
                acc[i][0] = fmaf(wv, g0, acc[i][0]);
                acc[i][1] = fmaf(wv, g1, acc[i][1]);
                acc[i][2] = fmaf(wv, g2, acc[i][2]);
                acc[i][3] = fmaf(wv, g3, acc[i][3]);
            }
        }
        #pragma unroll
        for (int i = 0; i < 8; i++)
            #pragma unroll
            for (int j = 0; j < 4; j++) pmax[i][j] = fmaxf(pmax[i][j], acc[i][j]);
    }

    float* outp = P1 + (((size_t)t * N_out + np) * C_out + co0) * B;
    float* pblk = part1c + (size_t)bid * 64;
    #pragma unroll
    for (int i = 0; i < 8; i++) {
        int co = cog * 8 + i;
        float bv = bias[co0 + co];
        float s = 0.f, s2 = 0.f;
        #pragma unroll
        for (int j = 0; j < 4; j++) {
            float val = pmax[i][j] + bv;
            outp[(size_t)co * B + bl + 64 * j] = val;
            s  += val;
            s2 += val * val;
        }
        for (int o = 32; o > 0; o >>= 1) {
            s  += __shfl_down(s,  o, 64);
            s2 += __shfl_down(s2, o, 64);
        }
        if ((tid & 63) == 0) {
            pblk[co]      = s;
            pblk[32 + co] = s2;
        }
    }
}

// ---------------------------------------------------------------------------
// BN1 stats from convpool1 partials
// ---------------------------------------------------------------------------
__global__ __launch_bounds__(256) void k_finstats1(
    const float* __restrict__ part1c,
    const float* __restrict__ gamma, const float* __restrict__ beta,
    float* __restrict__ scale, float* __restrict__ shift)
{
    int idx = blockIdx.x;            // t*64 + c
    int t = idx >> 6, c = idx & 63;
    int cot = c >> 5, cl = c & 31;
    float s = 0.f, s2 = 0.f;
    for (int np = threadIdx.x; np < 512; np += 256) {
        const float* pp = part1c + (size_t)((t * 512 + np) * 2 + cot) * 64;
        s  += pp[cl];
        s2 += pp[32 + cl];
    }
    __shared__ float lds[8];
    block_reduce2(s, s2, lds);
    if (threadIdx.x == 0) {
        float cnt  = 512.f * 256.f;
        float m    = s / cnt;
        float var  = s2 / cnt - m * m;
        float istd = rsqrtf(var + 1e-5f);
        float g    = gamma[c];
        scale[idx] = istd * g;
        shift[idx] = beta[c] - m * istd * g;
    }
}

// ---------------------------------------------------------------------------
// BN+relu + transpose: P1 fp32 [t][np][co][b] -> act1 bf16 [t][np][b][co]
// ---------------------------------------------------------------------------
__global__ __launch_bounds__(256) void k_bnrelu1t(
    const float* __restrict__ P1,
    const float* __restrict__ sc, const float* __restrict__ sh,
    __bf16* __restrict__ act1)
{
    int bid = blockIdx.x;
    int t = bid >> 9;
    int b = threadIdx.x;
    const float* src = P1 + (size_t)bid * 64 * B;
    __bf16* dst = act1 + (size_t)bid * B * 64 + (size_t)b * 64;
    const float* scp = sc + t * 64;
    const float* shp = sh + t * 64;
    __bf16 vals[64];
    #pragma unroll
    for (int co = 0; co < 64; co++) {
        float v = src[co * B + b];
        vals[co] = (__bf16)fmaxf(fmaf(v, scp[co], shp[co]), 0.f);
    }
    #pragma unroll
    for (int j = 0; j < 8; j++)
        *(bf16x8*)(dst + j * 8) = *(bf16x8*)&vals[j * 8];
}

// ---------------------------------------------------------------------------
// fused weight prep: Wr2/Wr3/Wr4 (re-layout to [co][kt][ci] bf16) + w1b (cvt8)
// ---------------------------------------------------------------------------
__global__ __launch_bounds__(256) void k_prep(
    const float* __restrict__ w2, const float* __restrict__ w3,
    const float* __restrict__ w4, const float* __restrict__ lw1,
    __bf16* __restrict__ Wr2, __bf16* __restrict__ Wr3,
    __bf16* __restrict__ Wr4, __bf16* __restrict__ w1b)
{
    const int n2 = 128 * 448, n3 = 256 * 896, n4 = 512 * 1792, n1 = (2048 * 4096) / 8;
    int idx = blockIdx.x * 256 + threadIdx.x;
    if (idx < n2) {
        int ci = idx & 63; int r = idx >> 6; int kt = r % 7; int co = r / 7;
        Wr2[idx] = (__bf16)w2[((size_t)co * 64 + ci) * 7 + kt];
        return;
    }
    idx -= n2;
    if (idx < n3) {
        int ci = idx & 127; int r = idx >> 7; int kt = r % 7; int co = r / 7;
        Wr3[idx] = (__bf16)w3[((size_t)co * 128 + ci) * 7 + kt];
        return;
    }
    idx -= n3;
    if (idx < n4) {
        int ci = idx & 255; int r = idx >> 8; int kt = r % 7; int co = r / 7;
        Wr4[idx] = (__bf16)w4[((size_t)co * 256 + ci) * 7 + kt];
        return;
    }
    idx -= n4;
    if (idx < n1) {
        const f32x4* s4 = (const f32x4*)(lw1 + (size_t)idx * 8);
        f32x4 a = s4[0], b = s4[1];
        bf16x8 v;
        v[0] = (__bf16)a[0]; v[1] = (__bf16)a[1]; v[2] = (__bf16)a[2]; v[3] = (__bf16)a[3];
        v[4] = (__bf16)b[0]; v[5] = (__bf16)b[1]; v[6] = (__bf16)b[2]; v[7] = (__bf16)b[3];
        *(bf16x8*)(w1b + (size_t)idx * 8) = v;
    }
}

// ---------------------------------------------------------------------------
// MFMA conv, co-tile 128, LDS-staged A (r5-style, proven <71us structure):
// per 32-K chunk: barrier / stage 128x32 weights to LDS / barrier / 4 global
// bfrag + 8 LDS afrag + 32 MFMA. Lockstep waves share the gather column's
// cache lines; only 4 VMEM issues/lane/iter. Depth-1 B prefetch across chunks.
// grid: nco * N * 2 (both t) ; block 256 (4 waves over b)
// ---------------------------------------------------------------------------
__global__ __launch_bounds__(256) void k_conv_mfma(
    const __bf16* __restrict__ act,
    __bf16* __restrict__ convo,
    const __bf16* __restrict__ wr,
    const int* __restrict__ idx_conv,   // [7][N]
    int C_in, int C_out, int N, int ci_shift)
{
    int nco = C_out >> 7;               // 128-wide co tiles
    int bid = blockIdx.x;
    int cot = bid % nco;
    int rem = bid / nco;
    int n   = rem % N;
    int t   = rem / N;
    int co0 = cot * 128;
    int Kt  = C_in * KW;

    __shared__ __bf16 lds_w[128 * LDSW];   // 9 KB

    int tid  = threadIdx.x;
    int wv   = tid >> 6;
    int lane = tid & 63;
    int quad = lane >> 4;
    int lid  = lane & 15;

    // preload all 7 gather-column indices (block-uniform -> SGPRs)
    int cols[KW];
    #pragma unroll
    for (int k = 0; k < KW; k++) cols[k] = idx_conv[k * N + n];

    f32x4 acc[8][4];
    #pragma unroll
    for (int i = 0; i < 8; i++)
        #pragma unroll
        for (int j = 0; j < 4; j++) {
            acc[i][j][0] = 0.f; acc[i][j][1] = 0.f;
            acc[i][j][2] = 0.f; acc[i][j][3] = 0.f;
        }

    const __bf16* actT = act + (size_t)t * N * B * C_in
                             + ((size_t)(wv * 64 + lid)) * C_in + quad * 8;
    // staging: thread -> row wco = tid>>1 (0..127), half wh = tid&1 (16 elems)
    int wco = tid >> 1;
    int wh  = tid & 1;
    const __bf16* wsrc = wr + (size_t)(co0 + wco) * Kt + wh * 16;

    int niter = Kt >> 5;

    bf16x8 bcur[4], bnxt[4];
    {
        const __bf16* g = actT + (size_t)cols[0] * B * C_in;
        #pragma unroll
        for (int bt = 0; bt < 4; bt++)
            bcur[bt] = *(const bf16x8*)(g + (size_t)bt * 16 * C_in);
    }

    for (int it = 0; it < niter; it++) {
        int k0 = it << 5;
        __syncthreads();   // protect lds_w reuse
        *(bf16x8*)&lds_w[wco * LDSW + wh * 16]     = *(const bf16x8*)(wsrc + k0);
        *(bf16x8*)&lds_w[wco * LDSW + wh * 16 + 8] = *(const bf16x8*)(wsrc + k0 + 8);
        __syncthreads();
        // prefetch next chunk's gathered B
        if (it + 1 < niter) {
            int k1  = k0 + 32;
            int kt  = k1 >> ci_shift;
            int ci0 = k1 & (C_in - 1);
            const __bf16* g = actT + (size_t)cols[kt] * B * C_in + ci0;
            #pragma unroll
            for (int bt = 0; bt < 4; bt++)
                bnxt[bt] = *(const bf16x8*)(g + (size_t)bt * 16 * C_in);
        }
        #pragma unroll
        for (int rt = 0; rt < 8; rt++) {
            bf16x8 afrag = *(const bf16x8*)&lds_w[(rt * 16 + lid) * LDSW + quad * 8];
            #pragma unroll
            for (int bt = 0; bt < 4; bt++)
                acc[rt][bt] = __builtin_amdgcn_mfma_f32_16x16x32_bf16(
                    afrag, bcur[bt], acc[rt][bt], 0, 0, 0);
        }
        #pragma unroll
        for (int bt = 0; bt < 4; bt++) bcur[bt] = bnxt[bt];
    }

    __bf16* outp = convo + ((size_t)(t * N + n) * B) * C_out;
    #pragma unroll
    for (int rt = 0; rt < 8; rt++)
        #pragma unroll
        for (int bt = 0; bt < 4; bt++) {
            int b  = wv * 64 + bt * 16 + lid;
            int co = co0 + rt * 16 + quad * 4;
            bf16x4 v;
            v[0] = (__bf16)acc[rt][bt][0];
            v[1] = (__bf16)acc[rt][bt][1];
            v[2] = (__bf16)acc[rt][bt][2];
            v[3] = (__bf16)acc[rt][bt][3];
            *(bf16x4*)(outp + (size_t)b * C_out + co) = v;
        }
}

// ---------------------------------------------------------------------------
// pool + bias + stats partials: convo bf16 [2][N][256][C] -> P fp32 [2][No][256][C]
// ---------------------------------------------------------------------------
__global__ __launch_bounds__(256) void k_poolstats(
    const __bf16* __restrict__ convo,
    float* __restrict__ P,
    const float* __restrict__ bias,
    const int* __restrict__ idx_pool,   // [7][No]
    float* __restrict__ part,
    int C, int N, int No)
{
    int bid  = blockIdx.x;
    int bg   = bid & 3;
    int rem  = bid >> 2;
    int np   = rem % No;
    int t    = rem / No;
    int cols[7];
    #pragma unroll
    for (int k = 0; k < 7; k++) cols[k] = idx_pool[k * No + np];
    const __bf16* base = convo + (size_t)t * N * B * C;
    float* pout = P + ((size_t)(t * No + np) * B) * C;
    int tid = threadIdx.x;
    float s[2] = {0.f, 0.f}, s2[2] = {0.f, 0.f};
    int NC, c0, bstart, bstep, nb;
    if (C >= 256) { NC = C >> 8; c0 = tid;           bstart = 0;        bstep = 1; nb = 64; }
    else          { NC = 1;      c0 = tid & (C - 1); bstart = tid >> 7; bstep = 2; nb = 32; }
    for (int j = 0; j < NC; j++) {
        int c = c0 + j * 256;
        float bv = bias[c];
        for (int i = 0; i < nb; i++) {
            int b = bg * 64 + bstart + i * bstep;
            float m = -1e30f;
            #pragma unroll
            for (int k = 0; k < 7; k++) {
                float v = (float)base[((size_t)cols[k] * B + b) * C + c];
                m = fmaxf(m, v);
            }
            float val = m + bv;
            pout[(size_t)b * C + c] = val;
            s[j] += val; s2[j] += val * val;
        }
    }
    float* pp = part + (size_t)((t * No + np) * 4 + bg) * 1024;
    for (int j = 0; j < NC; j++) {
        pp[tid + j * 256]       = s[j];
        pp[512 + tid + j * 256] = s2[j];
    }
}

// ---------------------------------------------------------------------------
// finalize BN stats from poolstats partials (one block per (t,c))
// ---------------------------------------------------------------------------
__global__ __launch_bounds__(256) void k_finstats(
    const float* __restrict__ part,
    const float* __restrict__ gamma, const float* __restrict__ beta,
    float* __restrict__ scale, float* __restrict__ shift,
    int C, int No)
{
    int idx = blockIdx.x;            // t*C + c
    int t = idx / C, c = idx - t * C;
    int SMAX   = C < 256 ? 256 : C;
    int nslice = SMAX / C;
    int nblk   = No * 4;
    int total  = nblk * nslice;
    const float* pbase = part + (size_t)(t * No * 4) * 1024;
    float s = 0.f, s2 = 0.f;
    for (int e = threadIdx.x; e < total; e += 256) {
        int blk = e / nslice;
        int j   = e - blk * nslice;
        const float* pp = pbase + (size_t)blk * 1024;
        int sl = c + j * C;
        s  += pp[sl];
        s2 += pp[512 + sl];
    }
    __shared__ float lds[8];
    block_reduce2(s, s2, lds);
    if (threadIdx.x == 0) {
        float cnt  = (float)No * 256.f;
        float m    = s / cnt;
        float var  = s2 / cnt - m * m;
        float istd = rsqrtf(var + 1e-5f);
        float g    = gamma[c];
        scale[idx] = istd * g;
        shift[idx] = beta[c] - m * istd * g;
    }
}

// ---------------------------------------------------------------------------
// BN+relu: P fp32 [2][No][256][C] -> act bf16 same layout
// ---------------------------------------------------------------------------
__global__ void k_bnrelu(const float* __restrict__ P, __bf16* __restrict__ act,
                         const float* __restrict__ scale, const float* __restrict__ shift,
                         int C, int total)
{
    int idx = blockIdx.x * 256 + threadIdx.x;
    if (idx >= total) return;
    int c = idx & (C - 1);
    int t = idx >= (total >> 1) ? 1 : 0;
    int tc = t * C + c;
    float v = P[idx];
    act[idx] = (__bf16)fmaxf(fmaf(v, scale[tc], shift[tc]), 0.f);
}

// ---------------------------------------------------------------------------
// z [b][4096] bf16 from P4 fp32 [2][8][256][512]: BN+relu+avg in fp32, one rounding
// ---------------------------------------------------------------------------
__global__ __launch_bounds__(256) void k_zbuild(const float* __restrict__ P4,
                                                const float* __restrict__ sc4,
                                                const float* __restrict__ sh4,
                                                __bf16* __restrict__ z)
{
    int b = blockIdx.x;
    int tid = threadIdx.x;
    for (int j = 0; j < 2; j++) {
        int c = tid + j * 256;
        float s0 = sc4[c],       h0 = sh4[c];
        float s1 = sc4[512 + c], h1 = sh4[512 + c];
        #pragma unroll
        for (int np = 0; np < 8; np++) {
            float v0 = P4[(((size_t)0 * 8 + np) * B + b) * 512 + c];
            float v1 = P4[(((size_t)1 * 8 + np) * B + b) * 512 + c];
            float y0 = fmaxf(fmaf(v0, s0, h0), 0.f);
            float y1 = fmaxf(fmaf(v1, s1, h1), 0.f);
            z[(size_t)b * 4096 + c * 8 + np] = (__bf16)(0.5f * (y0 + y1));
        }
    }
}

// ---------------------------------------------------------------------------
// lin1 MFMA, K-split x8, barrier-free
// ---------------------------------------------------------------------------
__global__ __launch_bounds__(256) void k_lin1_part(
    const __bf16* __restrict__ zb,    // [256][4096]
    const __bf16* __restrict__ w1b,   // [2048][4096]
    float* __restrict__ partL)        // [8][2048][256]
{
    int ht = blockIdx.x >> 3;
    int ks = blockIdx.x & 7;
    int h0 = ht * 64;
    int f_beg = ks * 512, f_end = f_beg + 512;

    int tid  = threadIdx.x;
    int wv   = tid >> 6;
    int lane = tid & 63;
    int quad = lane >> 4;
    int lid  = lane & 15;

    f32x4 acc[4][4];
    #pragma unroll
    for (int i = 0; i < 4; i++)
        #pragma unroll
        for (int j = 0; j < 4; j++) {
            acc[i][j][0] = 0.f; acc[i][j][1] = 0.f;
            acc[i][j][2] = 0.f; acc[i][j][3] = 0.f;
        }

    const __bf16* wbase = w1b + (size_t)(h0 + lid) * 4096 + quad * 8;
    const __bf16* zbase = zb + ((size_t)(wv * 64 + lid)) * 4096 + quad * 8;

    for (int f0 = f_beg; f0 < f_end; f0 += 32) {
        bf16x8 afrag[4];
        #pragma unroll
        for (int rt = 0; rt < 4; rt++)
            afrag[rt] = *(const bf16x8*)(wbase + (size_t)rt * 16 * 4096 + f0);
        bf16x8 bfrag[4];
        #pragma unroll
        for (int bt = 0; bt < 4; bt++)
            bfrag[bt] = *(const bf16x8*)(zbase + (size_t)bt * 16 * 4096 + f0);
        #pragma unroll
        for (int rt = 0; rt < 4; rt++)
            #pragma unroll
            for (int bt = 0; bt < 4; bt++)
                acc[rt][bt] = __builtin_amdgcn_mfma_f32_16x16x32_bf16(
                    afrag[rt], bfrag[bt], acc[rt][bt], 0, 0, 0);
    }
    float* outp = partL + (size_t)ks * 2048 * B;
    #pragma unroll
    for (int rt = 0; rt < 4; rt++)
        #pragma unroll
        for (int bt = 0; bt < 4; bt++) {
            int b = wv * 64 + bt * 16 + lid;
            int h = h0 + rt * 16 + quad * 4;
            #pragma unroll
            for (int r = 0; r < 4; r++)
                outp[(size_t)(h + r) * B + b] = acc[rt][bt][r];
        }
}

// ---------------------------------------------------------------------------
// reduce lin1 partials + bias -> o1, and BN5 stats, in one pass. grid 2048.
// ---------------------------------------------------------------------------
__global__ __launch_bounds__(256) void k_redstats5(
    const float* __restrict__ partL,  // [8][2048][256]
    const float* __restrict__ b1,
    const float* __restrict__ gamma5, const float* __restrict__ beta5,
    float* __restrict__ o1,           // [2048][256]
    float* __restrict__ scale5, float* __restrict__ shift5)
{
    int h = blockIdx.x;
    int b = threadIdx.x;
    float v = b1[h];
    #pragma unroll
    for (int s = 0; s < 8; s++)
        v += partL[((size_t)s * 2048 + h) * B + b];
    o1[(size_t)h * B + b] = v;
    float s1 = v, s2 = v * v;
    __shared__ float lds[8];
    block_reduce2(s1, s2, lds);
    if (threadIdx.x == 0) {
        float m    = s1 * (1.f / 256.f);
        float var  = s2 * (1.f / 256.f) - m * m;
        float istd = rsqrtf(var + 1e-5f);
        float g    = gamma5[h];
        scale5[h]  = istd * g;
        shift5[h]  = beta5[h] - m * istd * g;
    }
}

// ---------------------------------------------------------------------------
// final head
// ---------------------------------------------------------------------------
__global__ __launch_bounds__(256) void k_final(
    const float* __restrict__ o1,
    const float* __restrict__ scale5, const float* __restrict__ shift5,
    const float* __restrict__ w2, const float* __restrict__ b2,
    float* __restrict__ out)
{
    int b = blockIdx.x;
    int tid = threadIdx.x;
    float s0 = 0.f, s1 = 0.f, s2v = 0.f;
    for (int h = tid; h < 2048; h += 256) {
        float y = fmaxf(fmaf(o1[(size_t)h * B + b], scale5[h], shift5[h]), 0.f);
        s0  = fmaf(y, w2[h],        s0);
        s1  = fmaf(y, w2[2048 + h], s1);
        s2v = fmaf(y, w2[4096 + h], s2v);
    }
    for (int off = 32; off > 0; off >>= 1) {
        s0  += __shfl_down(s0,  off, 64);
        s1  += __shfl_down(s1,  off, 64);
        s2v += __shfl_down(s2v, off, 64);
    }
    __shared__ float lds[12];
    int wave = tid >> 6, lane = tid & 63;
    if (lane == 0) { lds[wave * 3] = s0; lds[wave * 3 + 1] = s1; lds[wave * 3 + 2] = s2v; }
    __syncthreads();
    if (tid == 0) {
        float o0 = lds[0] + lds[3] + lds[6] + lds[9]  + b2[0];
        float oa = lds[1] + lds[4] + lds[7] + lds[10] + b2[1];
        float ob = lds[2] + lds[5] + lds[8] + lds[11] + b2[2];
        float m   = fmaxf(o0, oa);
        float lse = m + logf(expf(o0 - m) + expf(oa - m));
        out[b * 3 + 0] = o0 - lse;
        out[b * 3 + 1] = oa - lse;
        out[b * 3 + 2] = ob;
    }
}

// ---------------------------------------------------------------------------
extern "C" void kernel_launch(void* const* d_in, const int* in_sizes, int n_in,
                              void* d_out, int out_size, void* d_ws, size_t ws_size,
                              hipStream_t stream) {
    (void)in_sizes; (void)n_in; (void)out_size; (void)ws_size;

    const float* x   = (const float*)d_in[0];
    const int*   ic1 = (const int*)d_in[1];
    const int*   ip1 = (const int*)d_in[2];
    const float* pW1 = (const float*)d_in[3];
    const float* pB1 = (const float*)d_in[4];
    const float* pG1 = (const float*)d_in[5];
    const float* pE1 = (const float*)d_in[6];
    const int*   ic2 = (const int*)d_in[7];
    const int*   ip2 = (const int*)d_in[8];
    const float* pW2 = (const float*)d_in[9];
    const float* pB2 = (const float*)d_in[10];
    const float* pG2 = (const float*)d_in[11];
    const float* pE2 = (const float*)d_in[12];
    const int*   ic3 = (const int*)d_in[13];
    const int*   ip3 = (const int*)d_in[14];
    const float* pW3 = (const float*)d_in[15];
    const float* pB3 = (const float*)d_in[16];
    const float* pG3 = (const float*)d_in[17];
    const float* pE3 = (const float*)d_in[18];
    const int*   ic4 = (const int*)d_in[19];
    const int*   ip4 = (const int*)d_in[20];
    const float* pW4 = (const float*)d_in[21];
    const float* pB4 = (const float*)d_in[22];
    const float* pG4 = (const float*)d_in[23];
    const float* pE4 = (const float*)d_in[24];
    const float* lw1 = (const float*)d_in[25];
    const float* lb1 = (const float*)d_in[26];
    const float* g5  = (const float*)d_in[27];
    const float* e5  = (const float*)d_in[28];
    const float* lw2 = (const float*)d_in[29];
    const float* lb2 = (const float*)d_in[30];

    char* ws = (char*)d_ws;
    size_t off = 0;
    auto alloc = [&](size_t bytes) -> char* {
        char* p = ws + off;
        off += (bytes + 511) & ~(size_t)511;
        return p;
    };

    float*  A0    = (float*) alloc((size_t)2 * 2048 * 2 * B * 4);      //   8.4 MB
    __bf16* act1  = (__bf16*)alloc((size_t)2 * 512 * B * 64 * 2);      //  33.5 MB
    char*   U     =          alloc((size_t)512 * B * 128 * 4);         //  67.1 MB
    float*  P1f   = (float*)U;            // layer-1 conv+pool out (dead after bnrelu1t)
    __bf16* convX = (__bf16*)U;           // bf16 conv out: L2 67MB, L3 33.5MB, L4 8.4MB
    float*  partL = (float*)U;            // lin1 K-split partials [8][2048][256] (16.8 MB)
    float*  Pf    = (float*) alloc((size_t)2 * 128 * B * 128 * 4);     //  33.5 MB
    __bf16* actS  = (__bf16*)alloc((size_t)2 * 128 * B * 128 * 2);     //  16.8 MB
    __bf16* Wr2   = (__bf16*)alloc((size_t)128 * 448 * 2);
    __bf16* Wr3   = (__bf16*)alloc((size_t)256 * 896 * 2);
    __bf16* Wr4   = (__bf16*)alloc((size_t)512 * 1792 * 2);
    __bf16* w1b   = (__bf16*)alloc((size_t)2048 * 4096 * 2);           //  16.8 MB
    __bf16* z     = (__bf16*)alloc((size_t)256 * 4096 * 2);            //   2.1 MB
    float*  o1    = (float*) alloc((size_t)2048 * B * 4);              //   2.1 MB
    float*  part  = (float*) alloc((size_t)2 * 128 * 4 * 1024 * 4);    //   4.2 MB
    float*  part1c= (float*) alloc((size_t)2048 * 64 * 4);             //   0.5 MB
    float*  sc1 = (float*)alloc(2 * 64 * 4);
    float*  sh1 = (float*)alloc(2 * 64 * 4);
    float*  sc2 = (float*)alloc(2 * 128 * 4);
    float*  sh2 = (float*)alloc(2 * 128 * 4);
    float*  sc3 = (float*)alloc(2 * 256 * 4);
    float*  sh3 = (float*)alloc(2 * 256 * 4);
    float*  sc4 = (float*)alloc(2 * 512 * 4);
    float*  sh4 = (float*)alloc(2 * 512 * 4);
    float*  sc5 = (float*)alloc(2048 * 4);
    float*  sh5 = (float*)alloc(2048 * 4);

    // fused weight prep (Wr2+Wr3+Wr4+w1b in one dispatch)
    {
        const int total = 128 * 448 + 256 * 896 + 512 * 1792 + (2048 * 4096) / 8;
        k_prep<<<(total + 255) / 256, 256, 0, stream>>>(pW2, pW3, pW4, lw1,
                                                        Wr2, Wr3, Wr4, w1b);
    }

    // input transform
    k_transpose<<<256, 256, 0, stream>>>(x, A0);

    // layer 1 (fp32; BN partials fused)
    k_convpool1<<<2048, 256, 0, stream>>>(A0, P1f, pW1, pB1, ic1, ip1, part1c);
    k_finstats1<<<2 * 64, 256, 0, stream>>>(part1c, pG1, pE1, sc1, sh1);
    k_bnrelu1t<<<2 * 512, 256, 0, stream>>>(P1f, sc1, sh1, act1);

    // layer 2: 64 -> 128, N 512 -> 128 (both branches; grid 1024)
    k_conv_mfma<<<1 * 512 * 2, 256, 0, stream>>>(act1, convX, Wr2, ic2, 64, 128, 512, 6);
    k_poolstats<<<2 * 128 * 4, 256, 0, stream>>>(convX, Pf, pB2, ip2, part, 128, 512, 128);
    k_finstats<<<2 * 128, 256, 0, stream>>>(part, pG2, pE2, sc2, sh2, 128, 128);
    k_bnrelu<<<(2 * 128 * B * 128) / 256, 256, 0, stream>>>(Pf, actS, sc2, sh2, 128, 2 * 128 * B * 128);

    // layer 3: 128 -> 256, N 128 -> 32 (grid 512)
    k_conv_mfma<<<2 * 128 * 2, 256, 0, stream>>>(actS, convX, Wr3, ic3, 128, 256, 128, 7);
    k_poolstats<<<2 * 32 * 4, 256, 0, stream>>>(convX, Pf, pB3, ip3, part, 256, 128, 32);
    k_finstats<<<2 * 256, 256, 0, stream>>>(part, pG3, pE3, sc3, sh3, 256, 32);
    k_bnrelu<<<(2 * 32 * B * 256) / 256, 256, 0, stream>>>(Pf, actS, sc3, sh3, 256, 2 * 32 * B * 256);

    // layer 4: 256 -> 512, N 32 -> 8 (grid 256)
    k_conv_mfma<<<4 * 32 * 2, 256, 0, stream>>>(actS, convX, Wr4, ic4, 256, 512, 32, 8);
    k_poolstats<<<2 * 8 * 4, 256, 0, stream>>>(convX, Pf, pB4, ip4, part, 512, 32, 8);
    k_finstats<<<2 * 512, 256, 0, stream>>>(part, pG4, pE4, sc4, sh4, 512, 8);

    // head
    k_zbuild<<<256, 256, 0, stream>>>(Pf, sc4, sh4, z);
    k_lin1_part<<<256, 256, 0, stream>>>(z, w1b, partL);
    k_redstats5<<<2048, 256, 0, stream>>>(partL, lb1, g5, e5, o1, sc5, sh5);
    k_final<<<256, 256, 0, stream>>>(o1, sc5, sh5, lw2, lb2, (float*)d_out);
}